// Round 20
// baseline (193.412 us; speedup 1.0000x reference)
//
#include <hip/hip_runtime.h>
#include <hip/hip_bf16.h>

#define BB 8
#define TT 2048
#define DD 512
#define SQRTD 22.62741699796952f

typedef float fv4 __attribute__((ext_vector_type(4)));
typedef short bv8 __attribute__((ext_vector_type(8)));
typedef short bv4 __attribute__((ext_vector_type(4)));

__device__ __forceinline__ short f2bf(float f) {
  __hip_bfloat16 h = __float2bfloat16(f);
  return *reinterpret_cast<short*>(&h);
}
__device__ __forceinline__ float bf2f(short s) {
  union { unsigned u; float f; } a; a.u = ((unsigned)(unsigned short)s) << 16;
  return a.f;
}

__device__ __forceinline__ void gld_lds16(const void* g, void* l) {
  __builtin_amdgcn_global_load_lds(
      (const __attribute__((address_space(1))) void*)g,
      (__attribute__((address_space(3))) void*)l, 16, 0, 0);
}

// ---------------- K0: cast W (f32 512x512 x3) -> bf16
__global__ __launch_bounds__(256) void k_castw(
    const float* __restrict__ Wq, const float* __restrict__ Wk,
    const float* __restrict__ Wv, short* __restrict__ Wb)
{
  const int z = blockIdx.y;
  const float* __restrict__ src = (z == 0) ? Wq : (z == 1) ? Wk : Wv;
  short* __restrict__ dst = Wb + (size_t)z * DD * DD;
  int i = blockIdx.x * 256 + threadIdx.x;          // 8 elems per thread
  fv4 a = ((const fv4*)src)[i * 2];
  fv4 b = ((const fv4*)src)[i * 2 + 1];
  bv8 h;
  #pragma unroll
  for (int e = 0; e < 4; ++e) { h[e] = f2bf(a[e]); h[4 + e] = f2bf(b[e]); }
  ((bv8*)dst)[i] = h;
}

// ---------------- K1: projection GEMM: C = X @ W^T (X f32, W bf16, C bf16)
// Tile 128m x 128n, BK=64, 512 thr / 8 waves (4M x 2N, wave = 32x64, acc=32).
// z==2 (V): epilogue writes Vt[b][d][t] via single 32KB swizzled LDS bounce.
__global__ __launch_bounds__(512, 4) void k_proj2(
    const float* __restrict__ Xq, const float* __restrict__ Xk, const float* __restrict__ Xv,
    const short* __restrict__ Wb,
    short* __restrict__ Qb, short* __restrict__ Kb, short* __restrict__ Vt)
{
  __shared__ __align__(16) char ShM[32768];   // Xs 16KB | Ws 16KB ; epi: Tb 32KB
  short* Xs = (short*)ShM;
  short* Ws = (short*)(ShM + 16384);
  const int z = blockIdx.z;
  const float* __restrict__ X = (z == 0) ? Xq : (z == 1) ? Xk : Xv;
  const short* __restrict__ W = Wb + (size_t)z * DD * DD;
  const int m0 = blockIdx.x * 128;
  const int n0 = blockIdx.y * 128;
  const int t = threadIdx.x;
  const int lane = t & 63;
  const int w = t >> 6;                 // 0..7
  const int wrg = (w >> 1) * 32;        // row base (4 groups)
  const int wcg = (w & 1) * 64;         // col base (2 groups)
  const int l15 = lane & 15, l4 = lane >> 4;
  fv4 acc[2][4] = {};
  for (int kt = 0; kt < DD; kt += 64) {
    #pragma unroll
    for (int j = 0; j < 2; ++j) {
      int f = j * 512 + t;
      int row = f >> 3, c8 = f & 7;
      gld_lds16(W + (size_t)(n0 + row) * DD + kt + ((c8 ^ (row & 7)) << 3),
                Ws + (size_t)f * 8);
    }
    #pragma unroll
    for (int j = 0; j < 4; ++j) {
      int f = j * 512 + t;
      int row = f >> 4, c4 = f & 15;
      fv4 va = *(const fv4*)(X + (size_t)(m0 + row) * DD + kt + c4 * 4);
      bv4 ha;
      #pragma unroll
      for (int e = 0; e < 4; ++e) ha[e] = f2bf(va[e]);
      *(bv4*)((char*)Xs + ((row * 128 + c4 * 8) ^ ((row & 7) << 4))) = ha;
    }
    __syncthreads();
    #pragma unroll
    for (int ks = 0; ks < 2; ++ks) {
      bv8 af[2], bfr[4];
      #pragma unroll
      for (int i = 0; i < 2; ++i) {
        int ra = wrg + i * 16 + l15;
        af[i] = *(bv8*)((char*)Xs + ((ra * 128 + ks * 64 + l4 * 16) ^ ((ra & 7) << 4)));
      }
      #pragma unroll
      for (int i = 0; i < 4; ++i) {
        int rb = wcg + i * 16 + l15;
        bfr[i] = *(bv8*)((char*)Ws + ((rb * 128 + ks * 64 + l4 * 16) ^ ((rb & 7) << 4)));
      }
      #pragma unroll
      for (int mi = 0; mi < 2; ++mi)
        #pragma unroll
        for (int ni = 0; ni < 4; ++ni)
          acc[mi][ni] = __builtin_amdgcn_mfma_f32_16x16x32_bf16(af[mi], bfr[ni], acc[mi][ni], 0, 0, 0);
    }
    __syncthreads();
  }
  if (z != 2) {
    short* __restrict__ C = (z == 0) ? Qb : Kb;
    #pragma unroll
    for (int mi = 0; mi < 2; ++mi)
      #pragma unroll
      for (int r = 0; r < 4; ++r) {
        int gm = m0 + wrg + mi * 16 + (l4 << 2) + r;
        #pragma unroll
        for (int ni = 0; ni < 4; ++ni) {
          int gn = n0 + wcg + ni * 16 + l15;
          C[(size_t)gm * DD + gn] = f2bf(acc[mi][ni][r]);
        }
      }
  } else {
    // V: write transposed Vt[b][d][t] via single 32KB LDS bounce
    const int b2 = m0 >> 11, t0l = m0 & (TT - 1);
    short* Tb = (short*)ShM;   // [128 d][128 t], swizzled 256B rows
    #pragma unroll
    for (int mi = 0; mi < 2; ++mi)
      #pragma unroll
      for (int r = 0; r < 4; ++r) {
        int tl = wrg + mi * 16 + (l4 << 2) + r;
        #pragma unroll
        for (int ni = 0; ni < 4; ++ni) {
          int dl = wcg + ni * 16 + l15;
          *(short*)((char*)Tb + ((dl * 256 + tl * 2) ^ ((dl & 7) << 4))) = f2bf(acc[mi][ni][r]);
        }
      }
    __syncthreads();
    #pragma unroll
    for (int c = 0; c < 4; ++c) {
      int f = c * 512 + t;
      int dl = f >> 4, ch = f & 15;
      bv8 v = *(const bv8*)((const char*)Tb + ((dl * 256 + ch * 16) ^ ((dl & 7) << 4)));
      *(bv8*)(Vt + ((size_t)b2 * DD + n0 + dl) * TT + t0l + ch * 8) = v;
    }
  }
}

// ---------------- K2: S-GEMM, glds-dbuf + mask-tile DMA into LDS.
// Tile 128x128, K=512, 512 thr / 8 waves (4M x 2N, wave 32x64, acc=32).
// Mask: 64KB f32 tile streamed by global_load_lds, 16 rows/iter (1 glds/thr),
// linear dest, 64B-chunk XOR-swizzled source (read-side XOR matches).
// vmcnt ledger: per-iter top vmcnt(1) retires QK(g), leaves M(g) in flight;
// final vmcnt(0)+barrier before the epilogue lands the full mask tile.
__global__ __launch_bounds__(512, 2) void k_sgemm(
    const short* __restrict__ Qb, const short* __restrict__ Kb,
    const float* __restrict__ mask, short* __restrict__ Pq,
    float* __restrict__ Lpart)
{
  __shared__ __align__(16) short Sh[4][128 * 64];  // 64KB QK dbuf; epi: Ps=Sh[0]
  __shared__ __align__(16) float Ml[128 * 128];    // 64KB mask tile
  const int b = blockIdx.z;
  const int m0 = blockIdx.x * 128;   // q rows
  const int ky = blockIdx.y;         // k-tile index
  const int n0 = ky * 128;           // k cols
  const int t = threadIdx.x;
  const int lane = t & 63;
  const int w = t >> 6;
  const int wrg = (w >> 1) * 32;
  const int wcg = (w & 1) * 64;
  const int l15 = lane & 15, l4 = lane >> 4;

  fv4 acc[2][4] = {};

  // prologue: stage QK buf0 (kt=0)
  #pragma unroll
  for (int j = 0; j < 2; ++j) {
    int f = j * 512 + t;
    int row = f >> 3, c8 = f & 7;
    int srcc = (c8 ^ (row & 7)) << 3;
    gld_lds16(Qb + ((size_t)b * TT + m0 + row) * DD + srcc, Sh[0] + (size_t)f * 8);
    gld_lds16(Kb + ((size_t)b * TT + n0 + row) * DD + srcc, Sh[1] + (size_t)f * 8);
  }
  __builtin_amdgcn_sched_barrier(0);

  #pragma unroll
  for (int g = 0; g < 8; ++g) {
    // top wait: retire QK(g); leave M(g-1) (and newer) in flight.
    if (g == 0)
      asm volatile("s_waitcnt vmcnt(0) lgkmcnt(0)\n\ts_barrier" ::: "memory");
    else
      asm volatile("s_waitcnt vmcnt(1) lgkmcnt(0)\n\ts_barrier" ::: "memory");
    // stage next QK k-tile into the other buffer
    if (g < 7) {
      short* Qs = Sh[((g & 1) ^ 1) * 2];
      short* Ks = Sh[((g & 1) ^ 1) * 2 + 1];
      const int kt = (g + 1) * 64;
      #pragma unroll
      for (int j = 0; j < 2; ++j) {
        int f = j * 512 + t;
        int row = f >> 3, c8 = f & 7;
        int srcc = (c8 ^ (row & 7)) << 3;
        gld_lds16(Qb + ((size_t)b * TT + m0 + row) * DD + kt + srcc, Qs + (size_t)f * 8);
        gld_lds16(Kb + ((size_t)b * TT + n0 + row) * DD + kt + srcc, Ks + (size_t)f * 8);
      }
    }
    __builtin_amdgcn_sched_barrier(0);  // QK glds strictly older than M glds in FIFO
    // mask tile DMA: 16 rows this iter; linear dest, 64B-chunk swizzled source
    {
      int f = g * 512 + t;              // chunk id 0..4095 (16B each)
      int row = f >> 5, ch = f & 31;
      int chs = ch ^ (((row >> 2) & 3) << 2);
      gld_lds16(mask + ((size_t)b * TT + m0 + row) * TT + n0 + chs * 4,
                (char*)Ml + (size_t)f * 16);
    }
    // compute from buf[g&1]
    const short* Qs = Sh[(g & 1) * 2];
    const short* Ks = Sh[(g & 1) * 2 + 1];
    #pragma unroll
    for (int ks = 0; ks < 2; ++ks) {
      bv8 af[2], bfr[4];
      #pragma unroll
      for (int i = 0; i < 2; ++i) {
        int ra = wrg + i * 16 + l15;
        af[i] = *(bv8*)((char*)Qs + ((ra * 128 + ks * 64 + (l4 * 16)) ^ ((ra & 7) << 4)));
      }
      #pragma unroll
      for (int i = 0; i < 4; ++i) {
        int rb = wcg + i * 16 + l15;
        bfr[i] = *(bv8*)((char*)Ks + ((rb * 128 + ks * 64 + (l4 * 16)) ^ ((rb & 7) << 4)));
      }
      #pragma unroll
      for (int mi = 0; mi < 2; ++mi)
        #pragma unroll
        for (int ni = 0; ni < 4; ++ni)
          acc[mi][ni] = __builtin_amdgcn_mfma_f32_16x16x32_bf16(af[mi], bfr[ni], acc[mi][ni], 0, 0, 0);
    }
  }
  // epilogue: all mask DMA + compute done; buf0 region free -> Ps (32 KB)
  asm volatile("s_waitcnt vmcnt(0) lgkmcnt(0)\n\ts_barrier" ::: "memory");
  short* Ps = Sh[0];   // 128 rows x 256 B, XOR-swizzled
  #pragma unroll
  for (int mi = 0; mi < 2; ++mi)
    #pragma unroll
    for (int r = 0; r < 4; ++r) {
      int row = wrg + mi * 16 + (l4 << 2) + r;
      #pragma unroll
      for (int ni = 0; ni < 4; ++ni) {
        int col = wcg + ni * 16 + l15;
        float mv = Ml[row * 128 + (col ^ (((row >> 2) & 3) << 4))];
        float sx = acc[mi][ni][r] * SQRTD + mv;
        *(short*)((char*)Ps + ((row * 256 + col * 2) ^ ((row & 7) << 4))) = f2bf(__expf(sx));
      }
    }
  __syncthreads();
  // store pass + per-row partial sums (deterministic, from the bf16 P itself)
  #pragma unroll
  for (int c = 0; c < 4; ++c) {
    int f = c * 512 + t;
    int row = f >> 4, ch = f & 15;
    bv8 v = *(const bv8*)((const char*)Ps + ((row * 256 + ch * 16) ^ ((row & 7) << 4)));
    *(bv8*)(Pq + ((size_t)b * TT + m0 + row) * TT + n0 + ch * 8) = v;
    float s8 = 0.f;
    #pragma unroll
    for (int e = 0; e < 8; ++e) s8 += bf2f(v[e]);
    s8 += __shfl_xor(s8, 1);
    s8 += __shfl_xor(s8, 2);
    s8 += __shfl_xor(s8, 4);
    s8 += __shfl_xor(s8, 8);
    if (ch == 0)
      Lpart[(size_t)ky * (BB * TT) + (size_t)b * TT + m0 + row] = s8;
  }
}

// ---------------- K3: O = (P @ Vt^T) / l.  Tile 128x128, K = 2048.
// 2-phase glds double-buffer (vmcnt(0) top wait, 1 barrier/iter).
__global__ __launch_bounds__(512, 4) void k_pv(
    const short* __restrict__ P, const short* __restrict__ Vt,
    const float* __restrict__ Lpart, float* __restrict__ Out)
{
  __shared__ __align__(16) short Sh[4][128 * 64];  // 64KB: buf0{A,B} buf1{A,B}
  __shared__ float Lrow[128];
  const int b = blockIdx.z;
  const int m0 = blockIdx.x * 128;
  const int n0 = blockIdx.y * 128;
  const int t = threadIdx.x;
  const int lane = t & 63;
  const int w = t >> 6;
  const int wrg = (w >> 1) * 32;
  const int wcg = (w & 1) * 64;
  const int l15 = lane & 15, l4 = lane >> 4;
  if (t < 128) {
    float s = 0.f;
    #pragma unroll
    for (int ky = 0; ky < 16; ++ky)
      s += Lpart[(size_t)ky * (BB * TT) + (size_t)b * TT + m0 + t];
    Lrow[t] = s;
  }
  // prologue: stage buf0 (kt=0)
  #pragma unroll
  for (int j = 0; j < 2; ++j) {
    int f = j * 512 + t;
    int row = f >> 3, c8 = f & 7;
    int srcc = (c8 ^ (row & 7)) << 3;
    gld_lds16(P + ((size_t)b * TT + m0 + row) * TT + 0 + srcc, (char*)Sh[0] + (size_t)f * 16);
    gld_lds16(Vt + ((size_t)b * DD + n0 + row) * TT + 0 + srcc, (char*)Sh[1] + (size_t)f * 16);
  }
  fv4 acc[2][4] = {};
  for (int g = 0; g < 32; ++g) {
    asm volatile("s_waitcnt vmcnt(0) lgkmcnt(0)\n\ts_barrier" ::: "memory");
    if (g < 31) {
      const int kt = (g + 1) * 64;
      char* At = (char*)Sh[((g & 1) ^ 1) * 2];
      char* Bt = (char*)Sh[((g & 1) ^ 1) * 2 + 1];
      #pragma unroll
      for (int j = 0; j < 2; ++j) {
        int f = j * 512 + t;
        int row = f >> 3, c8 = f & 7;
        int srcc = (c8 ^ (row & 7)) << 3;
        gld_lds16(P + ((size_t)b * TT + m0 + row) * TT + kt + srcc, At + (size_t)f * 16);
        gld_lds16(Vt + ((size_t)b * DD + n0 + row) * TT + kt + srcc, Bt + (size_t)f * 16);
      }
    }
    const char* At = (const char*)Sh[(g & 1) * 2];
    const char* Bt = (const char*)Sh[(g & 1) * 2 + 1];
    #pragma unroll
    for (int ks = 0; ks < 2; ++ks) {
      bv8 af[2], bfr[4];
      #pragma unroll
      for (int i = 0; i < 2; ++i) {
        int ra = wrg + i * 16 + l15;
        af[i] = *(bv8*)(At + ((ra * 128 + ks * 64 + (l4 * 16)) ^ ((ra & 7) << 4)));
      }
      #pragma unroll
      for (int i = 0; i < 4; ++i) {
        int rb = wcg + i * 16 + l15;
        bfr[i] = *(bv8*)(Bt + ((rb * 128 + ks * 64 + (l4 * 16)) ^ ((rb & 7) << 4)));
      }
      #pragma unroll
      for (int mi = 0; mi < 2; ++mi)
        #pragma unroll
        for (int ni = 0; ni < 4; ++ni)
          acc[mi][ni] = __builtin_amdgcn_mfma_f32_16x16x32_bf16(af[mi], bfr[ni], acc[mi][ni], 0, 0, 0);
    }
  }
  #pragma unroll
  for (int mi = 0; mi < 2; ++mi)
    #pragma unroll
    for (int r = 0; r < 4; ++r) {
      int ml = wrg + mi * 16 + (l4 << 2) + r;
      int gm = m0 + ml;
      float inv = 1.0f / Lrow[ml];
      #pragma unroll
      for (int ni = 0; ni < 4; ++ni) {
        int gn = n0 + wcg + ni * 16 + l15;
        Out[((size_t)b * TT + gm) * DD + gn] = acc[mi][ni][r] * inv;
      }
    }
}

extern "C" void kernel_launch(void* const* d_in, const int* in_sizes, int n_in,
                              void* d_out, int out_size, void* d_ws, size_t ws_size,
                              hipStream_t stream) {
  const float* ft_q = (const float*)d_in[0];
  const float* ft_k = (const float*)d_in[1];
  const float* ft_v = (const float*)d_in[2];
  const float* mask = (const float*)d_in[3];
  const float* Wq   = (const float*)d_in[4];
  const float* Wk   = (const float*)d_in[5];
  const float* Wv   = (const float*)d_in[6];
  float* Out = (float*)d_out;

  const size_t nBTD = (size_t)BB * TT * DD;   // 8,388,608
  const size_t nBTT = (size_t)BB * TT * TT;   // 33,554,432
  short* Qb = (short*)d_ws;
  short* Kb = Qb + nBTD;
  short* Vt = Kb + nBTD;
  short* Pq = Vt + nBTD;
  short* Wb = Pq + nBTT;                      // 3 x 512 x 512 bf16
  float* Lpart = (float*)(Wb + (size_t)3 * DD * DD);  // [16][B*T]

  k_castw<<<dim3(DD * DD / 8 / 256, 3), 256, 0, stream>>>(Wq, Wk, Wv, Wb);
  k_proj2<<<dim3(TT * BB / 128, DD / 128, 3), 512, 0, stream>>>(ft_q, ft_k, ft_v, Wb, Qb, Kb, Vt);
  k_sgemm<<<dim3(TT / 128, TT / 128, BB), 512, 0, stream>>>(Qb, Kb, mask, Pq, Lpart);
  k_pv<<<dim3(TT / 128, DD / 128, BB), 512, 0, stream>>>(Pq, Vt, Lpart, Out);
}

// Round 21
// 185.688 us; speedup vs baseline: 1.0416x; 1.0416x over previous
//
#include <hip/hip_runtime.h>
#include <hip/hip_bf16.h>

#define BB 8
#define TT 2048
#define DD 512
#define SQRTD 22.62741699796952f

typedef float fv4 __attribute__((ext_vector_type(4)));
typedef short bv8 __attribute__((ext_vector_type(8)));
typedef short bv4 __attribute__((ext_vector_type(4)));

__device__ __forceinline__ short f2bf(float f) {
  __hip_bfloat16 h = __float2bfloat16(f);
  return *reinterpret_cast<short*>(&h);
}
__device__ __forceinline__ float bf2f(short s) {
  union { unsigned u; float f; } a; a.u = ((unsigned)(unsigned short)s) << 16;
  return a.f;
}

__device__ __forceinline__ void gld_lds16(const void* g, void* l) {
  __builtin_amdgcn_global_load_lds(
      (const __attribute__((address_space(1))) void*)g,
      (__attribute__((address_space(3))) void*)l, 16, 0, 0);
}

// ---------------- K0: cast W (f32 512x512 x3) -> bf16
__global__ __launch_bounds__(256) void k_castw(
    const float* __restrict__ Wq, const float* __restrict__ Wk,
    const float* __restrict__ Wv, short* __restrict__ Wb)
{
  const int z = blockIdx.y;
  const float* __restrict__ src = (z == 0) ? Wq : (z == 1) ? Wk : Wv;
  short* __restrict__ dst = Wb + (size_t)z * DD * DD;
  int i = blockIdx.x * 256 + threadIdx.x;          // 8 elems per thread
  fv4 a = ((const fv4*)src)[i * 2];
  fv4 b = ((const fv4*)src)[i * 2 + 1];
  bv8 h;
  #pragma unroll
  for (int e = 0; e < 4; ++e) { h[e] = f2bf(a[e]); h[4 + e] = f2bf(b[e]); }
  ((bv8*)dst)[i] = h;
}

// ---------------- K1: projection GEMM: C = X @ W^T (X f32, W bf16, C bf16)
// Tile 128m x 128n, BK=64, 512 thr / 8 waves (4M x 2N, wave = 32x64, acc=32).
// z==2 (V): epilogue writes Vt[b][d][t] via single 32KB swizzled LDS bounce.
__global__ __launch_bounds__(512, 4) void k_proj2(
    const float* __restrict__ Xq, const float* __restrict__ Xk, const float* __restrict__ Xv,
    const short* __restrict__ Wb,
    short* __restrict__ Qb, short* __restrict__ Kb, short* __restrict__ Vt)
{
  __shared__ __align__(16) char ShM[32768];   // Xs 16KB | Ws 16KB ; epi: Tb 32KB
  short* Xs = (short*)ShM;
  short* Ws = (short*)(ShM + 16384);
  const int z = blockIdx.z;
  const float* __restrict__ X = (z == 0) ? Xq : (z == 1) ? Xk : Xv;
  const short* __restrict__ W = Wb + (size_t)z * DD * DD;
  const int m0 = blockIdx.x * 128;
  const int n0 = blockIdx.y * 128;
  const int t = threadIdx.x;
  const int lane = t & 63;
  const int w = t >> 6;                 // 0..7
  const int wrg = (w >> 1) * 32;        // row base (4 groups)
  const int wcg = (w & 1) * 64;         // col base (2 groups)
  const int l15 = lane & 15, l4 = lane >> 4;
  fv4 acc[2][4] = {};
  for (int kt = 0; kt < DD; kt += 64) {
    #pragma unroll
    for (int j = 0; j < 2; ++j) {
      int f = j * 512 + t;
      int row = f >> 3, c8 = f & 7;
      gld_lds16(W + (size_t)(n0 + row) * DD + kt + ((c8 ^ (row & 7)) << 3),
                Ws + (size_t)f * 8);
    }
    #pragma unroll
    for (int j = 0; j < 4; ++j) {
      int f = j * 512 + t;
      int row = f >> 4, c4 = f & 15;
      fv4 va = *(const fv4*)(X + (size_t)(m0 + row) * DD + kt + c4 * 4);
      bv4 ha;
      #pragma unroll
      for (int e = 0; e < 4; ++e) ha[e] = f2bf(va[e]);
      *(bv4*)((char*)Xs + ((row * 128 + c4 * 8) ^ ((row & 7) << 4))) = ha;
    }
    __syncthreads();
    #pragma unroll
    for (int ks = 0; ks < 2; ++ks) {
      bv8 af[2], bfr[4];
      #pragma unroll
      for (int i = 0; i < 2; ++i) {
        int ra = wrg + i * 16 + l15;
        af[i] = *(bv8*)((char*)Xs + ((ra * 128 + ks * 64 + l4 * 16) ^ ((ra & 7) << 4)));
      }
      #pragma unroll
      for (int i = 0; i < 4; ++i) {
        int rb = wcg + i * 16 + l15;
        bfr[i] = *(bv8*)((char*)Ws + ((rb * 128 + ks * 64 + l4 * 16) ^ ((rb & 7) << 4)));
      }
      #pragma unroll
      for (int mi = 0; mi < 2; ++mi)
        #pragma unroll
        for (int ni = 0; ni < 4; ++ni)
          acc[mi][ni] = __builtin_amdgcn_mfma_f32_16x16x32_bf16(af[mi], bfr[ni], acc[mi][ni], 0, 0, 0);
    }
    __syncthreads();
  }
  if (z != 2) {
    short* __restrict__ C = (z == 0) ? Qb : Kb;
    #pragma unroll
    for (int mi = 0; mi < 2; ++mi)
      #pragma unroll
      for (int r = 0; r < 4; ++r) {
        int gm = m0 + wrg + mi * 16 + (l4 << 2) + r;
        #pragma unroll
        for (int ni = 0; ni < 4; ++ni) {
          int gn = n0 + wcg + ni * 16 + l15;
          C[(size_t)gm * DD + gn] = f2bf(acc[mi][ni][r]);
        }
      }
  } else {
    // V: write transposed Vt[b][d][t] via single 32KB LDS bounce
    const int b2 = m0 >> 11, t0l = m0 & (TT - 1);
    short* Tb = (short*)ShM;   // [128 d][128 t], swizzled 256B rows
    #pragma unroll
    for (int mi = 0; mi < 2; ++mi)
      #pragma unroll
      for (int r = 0; r < 4; ++r) {
        int tl = wrg + mi * 16 + (l4 << 2) + r;
        #pragma unroll
        for (int ni = 0; ni < 4; ++ni) {
          int dl = wcg + ni * 16 + l15;
          *(short*)((char*)Tb + ((dl * 256 + tl * 2) ^ ((dl & 7) << 4))) = f2bf(acc[mi][ni][r]);
        }
      }
    __syncthreads();
    #pragma unroll
    for (int c = 0; c < 4; ++c) {
      int f = c * 512 + t;
      int dl = f >> 4, ch = f & 15;
      bv8 v = *(const bv8*)((const char*)Tb + ((dl * 256 + ch * 16) ^ ((dl & 7) << 4)));
      *(bv8*)(Vt + ((size_t)b2 * DD + n0 + dl) * TT + t0l + ch * 8) = v;
    }
  }
}

// ---------------- K2: S-GEMM, 2-iteration-deep glds pipeline.
// Tile 128x128, K=512, 512 thr / 8 waves (4M x 2N, wave 32x64, acc=32).
// Prologue stages k0+k1; iter g: counted-vmcnt top barrier -> compute buf(g)
// -> lgkm mid barrier -> issue glds(k_{g+2}) into freed buffer + mask(g+2).
// FIFO ledger (per wave): waits {12,16,12,12,12,12,12,4}, epilogue 0.
__global__ __launch_bounds__(512, 4) void k_sgemm(
    const short* __restrict__ Qb, const short* __restrict__ Kb,
    const float* __restrict__ mask, short* __restrict__ Pq,
    float* __restrict__ Lpart)
{
  __shared__ __align__(16) short Sh[4][128 * 64];  // 64KB: buf0{Q,K} buf1{Q,K}
  const int b = blockIdx.z;
  const int m0 = blockIdx.x * 128;   // q rows
  const int ky = blockIdx.y;         // k-tile index
  const int n0 = ky * 128;           // k cols
  const int t = threadIdx.x;
  const int lane = t & 63;
  const int w = t >> 6;
  const int wrg = (w >> 1) * 32;
  const int wcg = (w & 1) * 64;
  const int l15 = lane & 15, l4 = lane >> 4;

  float mk[8][4];
  fv4 acc[2][4] = {};

  // prologue: stage k0 -> buf0, k1 -> buf1, then mask groups 0,1
  #pragma unroll
  for (int j = 0; j < 2; ++j) {
    int f = j * 512 + t;
    int row = f >> 3, c8 = f & 7;
    int srcc = (c8 ^ (row & 7)) << 3;
    gld_lds16(Qb + ((size_t)b * TT + m0 + row) * DD + 0 + srcc, Sh[0] + (size_t)f * 8);
    gld_lds16(Kb + ((size_t)b * TT + n0 + row) * DD + 0 + srcc, Sh[1] + (size_t)f * 8);
  }
  __builtin_amdgcn_sched_barrier(0);
  #pragma unroll
  for (int j = 0; j < 2; ++j) {
    int f = j * 512 + t;
    int row = f >> 3, c8 = f & 7;
    int srcc = (c8 ^ (row & 7)) << 3;
    gld_lds16(Qb + ((size_t)b * TT + m0 + row) * DD + 64 + srcc, Sh[2] + (size_t)f * 8);
    gld_lds16(Kb + ((size_t)b * TT + n0 + row) * DD + 64 + srcc, Sh[3] + (size_t)f * 8);
  }
  __builtin_amdgcn_sched_barrier(0);
  #pragma unroll
  for (int g0 = 0; g0 < 2; ++g0) {
    int row = wrg + (g0 >> 2) * 16 + (l4 << 2) + (g0 & 3);
    const float* mrow = mask + ((size_t)b * TT + m0 + row) * TT + n0;
    #pragma unroll
    for (int ni = 0; ni < 4; ++ni)
      mk[g0][ni] = mrow[wcg + ni * 16 + l15];
  }

  #pragma unroll
  for (int g = 0; g < 8; ++g) {
    // top wait: retire glds(k_g) (and older masks); keep newer in flight.
    if (g == 0)
      asm volatile("s_waitcnt vmcnt(12) lgkmcnt(0)\n\ts_barrier" ::: "memory");
    else if (g == 1)
      asm volatile("s_waitcnt vmcnt(16) lgkmcnt(0)\n\ts_barrier" ::: "memory");
    else if (g == 7)
      asm volatile("s_waitcnt vmcnt(4) lgkmcnt(0)\n\ts_barrier" ::: "memory");
    else
      asm volatile("s_waitcnt vmcnt(12) lgkmcnt(0)\n\ts_barrier" ::: "memory");
    // compute from buf[g&1]
    {
      const short* Qs = Sh[(g & 1) * 2];
      const short* Ks = Sh[(g & 1) * 2 + 1];
      #pragma unroll
      for (int ks = 0; ks < 2; ++ks) {
        bv8 af[2], bfr[4];
        #pragma unroll
        for (int i = 0; i < 2; ++i) {
          int ra = wrg + i * 16 + l15;
          af[i] = *(bv8*)((char*)Qs + ((ra * 128 + ks * 64 + (l4 * 16)) ^ ((ra & 7) << 4)));
        }
        #pragma unroll
        for (int i = 0; i < 4; ++i) {
          int rb = wcg + i * 16 + l15;
          bfr[i] = *(bv8*)((char*)Ks + ((rb * 128 + ks * 64 + (l4 * 16)) ^ ((rb & 7) << 4)));
        }
        #pragma unroll
        for (int mi = 0; mi < 2; ++mi)
          #pragma unroll
          for (int ni = 0; ni < 4; ++ni)
            acc[mi][ni] = __builtin_amdgcn_mfma_f32_16x16x32_bf16(af[mi], bfr[ni], acc[mi][ni], 0, 0, 0);
      }
    }
    // mid barrier: all waves done reading buf[g&1]; safe to overwrite.
    asm volatile("s_waitcnt lgkmcnt(0)\n\ts_barrier" ::: "memory");
    if (g <= 5) {
      short* Qs = Sh[(g & 1) * 2];
      short* Ks = Sh[(g & 1) * 2 + 1];
      const int kt = (g + 2) * 64;
      #pragma unroll
      for (int j = 0; j < 2; ++j) {
        int f = j * 512 + t;
        int row = f >> 3, c8 = f & 7;
        int srcc = (c8 ^ (row & 7)) << 3;
        gld_lds16(Qb + ((size_t)b * TT + m0 + row) * DD + kt + srcc, Qs + (size_t)f * 8);
        gld_lds16(Kb + ((size_t)b * TT + n0 + row) * DD + kt + srcc, Ks + (size_t)f * 8);
      }
      __builtin_amdgcn_sched_barrier(0);   // glds strictly older than mask in FIFO
      int gm = g + 2;
      int row = wrg + (gm >> 2) * 16 + (l4 << 2) + (gm & 3);
      const float* mrow = mask + ((size_t)b * TT + m0 + row) * TT + n0;
      #pragma unroll
      for (int ni = 0; ni < 4; ++ni)
        mk[gm][ni] = mrow[wcg + ni * 16 + l15];
    }
  }
  // epilogue: retire mask(7); buf0 region free -> Ps (32 KB)
  asm volatile("s_waitcnt vmcnt(0) lgkmcnt(0)\n\ts_barrier" ::: "memory");
  short* Ps = Sh[0];   // 128 rows x 256 B, XOR-swizzled
  #pragma unroll
  for (int mi = 0; mi < 2; ++mi)
    #pragma unroll
    for (int r = 0; r < 4; ++r) {
      int row = wrg + mi * 16 + (l4 << 2) + r;
      #pragma unroll
      for (int ni = 0; ni < 4; ++ni) {
        int col = wcg + ni * 16 + l15;
        float sx = acc[mi][ni][r] * SQRTD + mk[mi * 4 + r][ni];
        *(short*)((char*)Ps + ((row * 256 + col * 2) ^ ((row & 7) << 4))) = f2bf(__expf(sx));
      }
    }
  __syncthreads();
  // store pass + per-row partial sums (deterministic, from the bf16 P itself)
  #pragma unroll
  for (int c = 0; c < 4; ++c) {
    int f = c * 512 + t;
    int row = f >> 4, ch = f & 15;
    bv8 v = *(const bv8*)((const char*)Ps + ((row * 256 + ch * 16) ^ ((row & 7) << 4)));
    *(bv8*)(Pq + ((size_t)b * TT + m0 + row) * TT + n0 + ch * 8) = v;
    float s8 = 0.f;
    #pragma unroll
    for (int e = 0; e < 8; ++e) s8 += bf2f(v[e]);
    s8 += __shfl_xor(s8, 1);
    s8 += __shfl_xor(s8, 2);
    s8 += __shfl_xor(s8, 4);
    s8 += __shfl_xor(s8, 8);
    if (ch == 0)
      Lpart[(size_t)ky * (BB * TT) + (size_t)b * TT + m0 + row] = s8;
  }
}

// ---------------- K3: O = (P @ Vt^T) / l.  Tile 128x128, K = 2048.
// 2-iteration-deep glds pipeline: prologue stages T0+T1; iter g waits vmcnt(4)
// (retires T_g, leaves T_{g+1}), computes, mid lgkm barrier, issues T_{g+2}.
__global__ __launch_bounds__(512, 4) void k_pv(
    const short* __restrict__ P, const short* __restrict__ Vt,
    const float* __restrict__ Lpart, float* __restrict__ Out)
{
  __shared__ __align__(16) short Sh[4][128 * 64];  // 64KB: buf0{A,B} buf1{A,B}
  __shared__ float Lrow[128];
  const int b = blockIdx.z;
  const int m0 = blockIdx.x * 128;
  const int n0 = blockIdx.y * 128;
  const int t = threadIdx.x;
  const int lane = t & 63;
  const int w = t >> 6;
  const int wrg = (w >> 1) * 32;
  const int wcg = (w & 1) * 64;
  const int l15 = lane & 15, l4 = lane >> 4;
  if (t < 128) {
    float s = 0.f;
    #pragma unroll
    for (int ky = 0; ky < 16; ++ky)
      s += Lpart[(size_t)ky * (BB * TT) + (size_t)b * TT + m0 + t];
    Lrow[t] = s;
  }
  // prologue: stage T0 -> buf0, T1 -> buf1
  #pragma unroll
  for (int j = 0; j < 2; ++j) {
    int f = j * 512 + t;
    int row = f >> 3, c8 = f & 7;
    int srcc = (c8 ^ (row & 7)) << 3;
    gld_lds16(P + ((size_t)b * TT + m0 + row) * TT + 0 + srcc, (char*)Sh[0] + (size_t)f * 16);
    gld_lds16(Vt + ((size_t)b * DD + n0 + row) * TT + 0 + srcc, (char*)Sh[1] + (size_t)f * 16);
  }
  __builtin_amdgcn_sched_barrier(0);
  #pragma unroll
  for (int j = 0; j < 2; ++j) {
    int f = j * 512 + t;
    int row = f >> 3, c8 = f & 7;
    int srcc = (c8 ^ (row & 7)) << 3;
    gld_lds16(P + ((size_t)b * TT + m0 + row) * TT + 64 + srcc, (char*)Sh[2] + (size_t)f * 16);
    gld_lds16(Vt + ((size_t)b * DD + n0 + row) * TT + 64 + srcc, (char*)Sh[3] + (size_t)f * 16);
  }
  __builtin_amdgcn_sched_barrier(0);
  fv4 acc[2][4] = {};
  for (int g = 0; g < 32; ++g) {
    if (g < 31)
      asm volatile("s_waitcnt vmcnt(4) lgkmcnt(0)\n\ts_barrier" ::: "memory");
    else
      asm volatile("s_waitcnt vmcnt(0) lgkmcnt(0)\n\ts_barrier" ::: "memory");
    const char* At = (const char*)Sh[(g & 1) * 2];
    const char* Bt = (const char*)Sh[(g & 1) * 2 + 1];
    #pragma unroll
    for (int ks = 0; ks < 2; ++ks) {
      bv8 af[2], bfr[4];
      #pragma unroll
      for (int i = 0; i < 2; ++i) {
        int ra = wrg + i * 16 + l15;
        af[i] = *(bv8*)(At + ((ra * 128 + ks * 64 + (l4 * 16)) ^ ((ra & 7) << 4)));
      }
      #pragma unroll
      for (int i = 0; i < 4; ++i) {
        int rb = wcg + i * 16 + l15;
        bfr[i] = *(bv8*)(Bt + ((rb * 128 + ks * 64 + (l4 * 16)) ^ ((rb & 7) << 4)));
      }
      #pragma unroll
      for (int mi = 0; mi < 2; ++mi)
        #pragma unroll
        for (int ni = 0; ni < 4; ++ni)
          acc[mi][ni] = __builtin_amdgcn_mfma_f32_16x16x32_bf16(af[mi], bfr[ni], acc[mi][ni], 0, 0, 0);
    }
    // mid barrier: all waves done reading buf[g&1]; safe to overwrite.
    asm volatile("s_waitcnt lgkmcnt(0)\n\ts_barrier" ::: "memory");
    if (g < 30) {
      const int kt = (g + 2) * 64;
      char* Atw = (char*)Sh[(g & 1) * 2];
      char* Btw = (char*)Sh[(g & 1) * 2 + 1];
      #pragma unroll
      for (int j = 0; j < 2; ++j) {
        int f = j * 512 + t;
        int row = f >> 3, c8 = f & 7;
        int srcc = (c8 ^ (row & 7)) << 3;
        gld_lds16(P + ((size_t)b * TT + m0 + row) * TT + kt + srcc, Atw + (size_t)f * 16);
        gld_lds16(Vt + ((size_t)b * DD + n0 + row) * TT + kt + srcc, Btw + (size_t)f * 16);
      }
    }
  }
  #pragma unroll
  for (int mi = 0; mi < 2; ++mi)
    #pragma unroll
    for (int r = 0; r < 4; ++r) {
      int ml = wrg + mi * 16 + (l4 << 2) + r;
      int gm = m0 + ml;
      float inv = 1.0f / Lrow[ml];
      #pragma unroll
      for (int ni = 0; ni < 4; ++ni) {
        int gn = n0 + wcg + ni * 16 + l15;
        Out[((size_t)b * TT + gm) * DD + gn] = acc[mi][ni][r] * inv;
      }
    }
}

extern "C" void kernel_launch(void* const* d_in, const int* in_sizes, int n_in,
                              void* d_out, int out_size, void* d_ws, size_t ws_size,
                              hipStream_t stream) {
  const float* ft_q = (const float*)d_in[0];
  const float* ft_k = (const float*)d_in[1];
  const float* ft_v = (const float*)d_in[2];
  const float* mask = (const float*)d_in[3];
  const float* Wq   = (const float*)d_in[4];
  const float* Wk   = (const float*)d_in[5];
  const float* Wv   = (const float*)d_in[6];
  float* Out = (float*)d_out;

  const size_t nBTD = (size_t)BB * TT * DD;   // 8,388,608
  const size_t nBTT = (size_t)BB * TT * TT;   // 33,554,432
  short* Qb = (short*)d_ws;
  short* Kb = Qb + nBTD;
  short* Vt = Kb + nBTD;
  short* Pq = Vt + nBTD;
  short* Wb = Pq + nBTT;                      // 3 x 512 x 512 bf16
  float* Lpart = (float*)(Wb + (size_t)3 * DD * DD);  // [16][B*T]

  k_castw<<<dim3(DD * DD / 8 / 256, 3), 256, 0, stream>>>(Wq, Wk, Wv, Wb);
  k_proj2<<<dim3(TT * BB / 128, DD / 128, 3), 512, 0, stream>>>(ft_q, ft_k, ft_v, Wb, Qb, Kb, Vt);
  k_sgemm<<<dim3(TT / 128, TT / 128, BB), 512, 0, stream>>>(Qb, Kb, mask, Pq, Lpart);
  k_pv<<<dim3(TT / 128, DD / 128, BB), 512, 0, stream>>>(Pq, Vt, Lpart, Out);
}

// Round 22
// 164.695 us; speedup vs baseline: 1.1744x; 1.1275x over previous
//
#include <hip/hip_runtime.h>
#include <hip/hip_bf16.h>

#define BB 8
#define TT 2048
#define DD 512
#define SQRTD 22.62741699796952f

typedef float fv4 __attribute__((ext_vector_type(4)));
typedef short bv8 __attribute__((ext_vector_type(8)));
typedef short bv4 __attribute__((ext_vector_type(4)));

__device__ __forceinline__ short f2bf(float f) {
  __hip_bfloat16 h = __float2bfloat16(f);
  return *reinterpret_cast<short*>(&h);
}
__device__ __forceinline__ float bf2f(short s) {
  union { unsigned u; float f; } a; a.u = ((unsigned)(unsigned short)s) << 16;
  return a.f;
}

__device__ __forceinline__ void gld_lds16(const void* g, void* l) {
  __builtin_amdgcn_global_load_lds(
      (const __attribute__((address_space(1))) void*)g,
      (__attribute__((address_space(3))) void*)l, 16, 0, 0);
}

// ---------------- K0: cast W (f32 512x512 x3) -> bf16
__global__ __launch_bounds__(256) void k_castw(
    const float* __restrict__ Wq, const float* __restrict__ Wk,
    const float* __restrict__ Wv, short* __restrict__ Wb)
{
  const int z = blockIdx.y;
  const float* __restrict__ src = (z == 0) ? Wq : (z == 1) ? Wk : Wv;
  short* __restrict__ dst = Wb + (size_t)z * DD * DD;
  int i = blockIdx.x * 256 + threadIdx.x;          // 8 elems per thread
  fv4 a = ((const fv4*)src)[i * 2];
  fv4 b = ((const fv4*)src)[i * 2 + 1];
  bv8 h;
  #pragma unroll
  for (int e = 0; e < 4; ++e) { h[e] = f2bf(a[e]); h[4 + e] = f2bf(b[e]); }
  ((bv8*)dst)[i] = h;
}

// ---------------- K1: projection GEMM: C = X @ W^T (X f32, W bf16, C bf16)
// Tile 128m x 128n, BK=64, 512 thr / 8 waves (4M x 2N, wave = 32x64, acc=32).
// z==2 (V): epilogue writes Vt[b][d][t] via single 32KB swizzled LDS bounce.
__global__ __launch_bounds__(512, 4) void k_proj2(
    const float* __restrict__ Xq, const float* __restrict__ Xk, const float* __restrict__ Xv,
    const short* __restrict__ Wb,
    short* __restrict__ Qb, short* __restrict__ Kb, short* __restrict__ Vt)
{
  __shared__ __align__(16) char ShM[32768];   // Xs 16KB | Ws 16KB ; epi: Tb 32KB
  short* Xs = (short*)ShM;
  short* Ws = (short*)(ShM + 16384);
  const int z = blockIdx.z;
  const float* __restrict__ X = (z == 0) ? Xq : (z == 1) ? Xk : Xv;
  const short* __restrict__ W = Wb + (size_t)z * DD * DD;
  const int m0 = blockIdx.x * 128;
  const int n0 = blockIdx.y * 128;
  const int t = threadIdx.x;
  const int lane = t & 63;
  const int w = t >> 6;                 // 0..7
  const int wrg = (w >> 1) * 32;        // row base (4 groups)
  const int wcg = (w & 1) * 64;         // col base (2 groups)
  const int l15 = lane & 15, l4 = lane >> 4;
  fv4 acc[2][4] = {};
  for (int kt = 0; kt < DD; kt += 64) {
    #pragma unroll
    for (int j = 0; j < 2; ++j) {
      int f = j * 512 + t;
      int row = f >> 3, c8 = f & 7;
      gld_lds16(W + (size_t)(n0 + row) * DD + kt + ((c8 ^ (row & 7)) << 3),
                Ws + (size_t)f * 8);
    }
    #pragma unroll
    for (int j = 0; j < 4; ++j) {
      int f = j * 512 + t;
      int row = f >> 4, c4 = f & 15;
      fv4 va = *(const fv4*)(X + (size_t)(m0 + row) * DD + kt + c4 * 4);
      bv4 ha;
      #pragma unroll
      for (int e = 0; e < 4; ++e) ha[e] = f2bf(va[e]);
      *(bv4*)((char*)Xs + ((row * 128 + c4 * 8) ^ ((row & 7) << 4))) = ha;
    }
    __syncthreads();
    #pragma unroll
    for (int ks = 0; ks < 2; ++ks) {
      bv8 af[2], bfr[4];
      #pragma unroll
      for (int i = 0; i < 2; ++i) {
        int ra = wrg + i * 16 + l15;
        af[i] = *(bv8*)((char*)Xs + ((ra * 128 + ks * 64 + l4 * 16) ^ ((ra & 7) << 4)));
      }
      #pragma unroll
      for (int i = 0; i < 4; ++i) {
        int rb = wcg + i * 16 + l15;
        bfr[i] = *(bv8*)((char*)Ws + ((rb * 128 + ks * 64 + l4 * 16) ^ ((rb & 7) << 4)));
      }
      #pragma unroll
      for (int mi = 0; mi < 2; ++mi)
        #pragma unroll
        for (int ni = 0; ni < 4; ++ni)
          acc[mi][ni] = __builtin_amdgcn_mfma_f32_16x16x32_bf16(af[mi], bfr[ni], acc[mi][ni], 0, 0, 0);
    }
    __syncthreads();
  }
  if (z != 2) {
    short* __restrict__ C = (z == 0) ? Qb : Kb;
    #pragma unroll
    for (int mi = 0; mi < 2; ++mi)
      #pragma unroll
      for (int r = 0; r < 4; ++r) {
        int gm = m0 + wrg + mi * 16 + (l4 << 2) + r;
        #pragma unroll
        for (int ni = 0; ni < 4; ++ni) {
          int gn = n0 + wcg + ni * 16 + l15;
          C[(size_t)gm * DD + gn] = f2bf(acc[mi][ni][r]);
        }
      }
  } else {
    // V: write transposed Vt[b][d][t] via single 32KB LDS bounce
    const int b2 = m0 >> 11, t0l = m0 & (TT - 1);
    short* Tb = (short*)ShM;   // [128 d][128 t], swizzled 256B rows
    #pragma unroll
    for (int mi = 0; mi < 2; ++mi)
      #pragma unroll
      for (int r = 0; r < 4; ++r) {
        int tl = wrg + mi * 16 + (l4 << 2) + r;
        #pragma unroll
        for (int ni = 0; ni < 4; ++ni) {
          int dl = wcg + ni * 16 + l15;
          *(short*)((char*)Tb + ((dl * 256 + tl * 2) ^ ((dl & 7) << 4))) = f2bf(acc[mi][ni][r]);
        }
      }
    __syncthreads();
    #pragma unroll
    for (int c = 0; c < 4; ++c) {
      int f = c * 512 + t;
      int dl = f >> 4, ch = f & 15;
      bv8 v = *(const bv8*)((const char*)Tb + ((dl * 256 + ch * 16) ^ ((dl & 7) << 4)));
      *(bv8*)(Vt + ((size_t)b2 * DD + n0 + dl) * TT + t0l + ch * 8) = v;
    }
  }
}

// ---------------- K2: S-GEMM, 2-phase glds double-buffer (r19 best config).
// Tile 128x128, K=512, 512 thr / 8 waves (4M x 2N, wave 32x64, acc=32).
// Mask loads NON-TEMPORAL (read-once stream; don't thrash L2/L3).
__global__ __launch_bounds__(512, 4) void k_sgemm(
    const short* __restrict__ Qb, const short* __restrict__ Kb,
    const float* __restrict__ mask, short* __restrict__ Pq,
    float* __restrict__ Lpart)
{
  __shared__ __align__(16) short Sh[4][128 * 64];  // 64KB: buf0{Q,K} buf1{Q,K}
  const int b = blockIdx.z;
  const int m0 = blockIdx.x * 128;   // q rows
  const int ky = blockIdx.y;         // k-tile index
  const int n0 = ky * 128;           // k cols
  const int t = threadIdx.x;
  const int lane = t & 63;
  const int w = t >> 6;
  const int wrg = (w >> 1) * 32;
  const int wcg = (w & 1) * 64;
  const int l15 = lane & 15, l4 = lane >> 4;

  float mk[8][4];
  fv4 acc[2][4] = {};

  // prologue: stage buf0 (kt=0) [fence] then mask groups 0,1
  {
    short* Qs = Sh[0];
    short* Ks = Sh[1];
    #pragma unroll
    for (int j = 0; j < 2; ++j) {
      int f = j * 512 + t;
      int row = f >> 3, c8 = f & 7;
      int srcc = (c8 ^ (row & 7)) << 3;
      gld_lds16(Qb + ((size_t)b * TT + m0 + row) * DD + 0 + srcc, Qs + (size_t)f * 8);
      gld_lds16(Kb + ((size_t)b * TT + n0 + row) * DD + 0 + srcc, Ks + (size_t)f * 8);
    }
  }
  __builtin_amdgcn_sched_barrier(0);   // glds strictly before mask in vmcnt FIFO
  #pragma unroll
  for (int g0 = 0; g0 < 2; ++g0) {
    int row = wrg + (g0 >> 2) * 16 + (l4 << 2) + (g0 & 3);
    const float* mrow = mask + ((size_t)b * TT + m0 + row) * TT + n0;
    #pragma unroll
    for (int ni = 0; ni < 4; ++ni)
      mk[g0][ni] = __builtin_nontemporal_load(mrow + wcg + ni * 16 + l15);
  }

  #pragma unroll
  for (int g = 0; g < 8; ++g) {
    // top wait: retire mask(g)+glds(g); keep mask(g+1) in flight.
    if (g == 7)
      asm volatile("s_waitcnt vmcnt(0) lgkmcnt(0)\n\ts_barrier" ::: "memory");
    else
      asm volatile("s_waitcnt vmcnt(4) lgkmcnt(0)\n\ts_barrier" ::: "memory");
    // stage next k-tile into the other buffer
    if (g < 7) {
      short* Qs = Sh[((g & 1) ^ 1) * 2];
      short* Ks = Sh[((g & 1) ^ 1) * 2 + 1];
      const int kt = (g + 1) * 64;
      #pragma unroll
      for (int j = 0; j < 2; ++j) {
        int f = j * 512 + t;
        int row = f >> 3, c8 = f & 7;
        int srcc = (c8 ^ (row & 7)) << 3;
        gld_lds16(Qb + ((size_t)b * TT + m0 + row) * DD + kt + srcc, Qs + (size_t)f * 8);
        gld_lds16(Kb + ((size_t)b * TT + n0 + row) * DD + kt + srcc, Ks + (size_t)f * 8);
      }
    }
    __builtin_amdgcn_sched_barrier(0);  // glds cluster closed; masks+compute mix freely
    // mask prefetch, 2 iterations deep (issues after glds; sinks into compute)
    if (g < 6) {
      int gm = g + 2;
      int row = wrg + (gm >> 2) * 16 + (l4 << 2) + (gm & 3);
      const float* mrow = mask + ((size_t)b * TT + m0 + row) * TT + n0;
      #pragma unroll
      for (int ni = 0; ni < 4; ++ni)
        mk[gm][ni] = __builtin_nontemporal_load(mrow + wcg + ni * 16 + l15);
    }
    // compute from buf[g&1]
    const short* Qs = Sh[(g & 1) * 2];
    const short* Ks = Sh[(g & 1) * 2 + 1];
    #pragma unroll
    for (int ks = 0; ks < 2; ++ks) {
      bv8 af[2], bfr[4];
      #pragma unroll
      for (int i = 0; i < 2; ++i) {
        int ra = wrg + i * 16 + l15;
        af[i] = *(bv8*)((char*)Qs + ((ra * 128 + ks * 64 + (l4 * 16)) ^ ((ra & 7) << 4)));
      }
      #pragma unroll
      for (int i = 0; i < 4; ++i) {
        int rb = wcg + i * 16 + l15;
        bfr[i] = *(bv8*)((char*)Ks + ((rb * 128 + ks * 64 + (l4 * 16)) ^ ((rb & 7) << 4)));
      }
      #pragma unroll
      for (int mi = 0; mi < 2; ++mi)
        #pragma unroll
        for (int ni = 0; ni < 4; ++ni)
          acc[mi][ni] = __builtin_amdgcn_mfma_f32_16x16x32_bf16(af[mi], bfr[ni], acc[mi][ni], 0, 0, 0);
    }
  }
  // epilogue: all waves past final barrier; buf0 region free -> Ps (32 KB)
  asm volatile("s_waitcnt lgkmcnt(0)\n\ts_barrier" ::: "memory");
  short* Ps = Sh[0];   // 128 rows x 256 B, XOR-swizzled
  #pragma unroll
  for (int mi = 0; mi < 2; ++mi)
    #pragma unroll
    for (int r = 0; r < 4; ++r) {
      int row = wrg + mi * 16 + (l4 << 2) + r;
      #pragma unroll
      for (int ni = 0; ni < 4; ++ni) {
        int col = wcg + ni * 16 + l15;
        float sx = acc[mi][ni][r] * SQRTD + mk[mi * 4 + r][ni];
        *(short*)((char*)Ps + ((row * 256 + col * 2) ^ ((row & 7) << 4))) = f2bf(__expf(sx));
      }
    }
  __syncthreads();
  // store pass + per-row partial sums (deterministic, from the bf16 P itself)
  #pragma unroll
  for (int c = 0; c < 4; ++c) {
    int f = c * 512 + t;
    int row = f >> 4, ch = f & 15;
    bv8 v = *(const bv8*)((const char*)Ps + ((row * 256 + ch * 16) ^ ((row & 7) << 4)));
    *(bv8*)(Pq + ((size_t)b * TT + m0 + row) * TT + n0 + ch * 8) = v;
    float s8 = 0.f;
    #pragma unroll
    for (int e = 0; e < 8; ++e) s8 += bf2f(v[e]);
    s8 += __shfl_xor(s8, 1);
    s8 += __shfl_xor(s8, 2);
    s8 += __shfl_xor(s8, 4);
    s8 += __shfl_xor(s8, 8);
    if (ch == 0)
      Lpart[(size_t)ky * (BB * TT) + (size_t)b * TT + m0 + row] = s8;
  }
}

// ---------------- K3: O = (P @ Vt^T) / l.  Tile 128x128, K = 2048.
// 2-phase glds double-buffer (r19 best config). Out stores NON-TEMPORAL
// (written once, never re-read; don't evict P/Vt from L2/L3).
__global__ __launch_bounds__(512, 4) void k_pv(
    const short* __restrict__ P, const short* __restrict__ Vt,
    const float* __restrict__ Lpart, float* __restrict__ Out)
{
  __shared__ __align__(16) short Sh[4][128 * 64];  // 64KB: buf0{A,B} buf1{A,B}
  __shared__ float Lrow[128];
  const int b = blockIdx.z;
  const int m0 = blockIdx.x * 128;
  const int n0 = blockIdx.y * 128;
  const int t = threadIdx.x;
  const int lane = t & 63;
  const int w = t >> 6;
  const int wrg = (w >> 1) * 32;
  const int wcg = (w & 1) * 64;
  const int l15 = lane & 15, l4 = lane >> 4;
  if (t < 128) {
    float s = 0.f;
    #pragma unroll
    for (int ky = 0; ky < 16; ++ky)
      s += Lpart[(size_t)ky * (BB * TT) + (size_t)b * TT + m0 + t];
    Lrow[t] = s;
  }
  // prologue: stage buf0 (kt=0)
  #pragma unroll
  for (int j = 0; j < 2; ++j) {
    int f = j * 512 + t;
    int row = f >> 3, c8 = f & 7;
    int srcc = (c8 ^ (row & 7)) << 3;
    gld_lds16(P + ((size_t)b * TT + m0 + row) * TT + 0 + srcc, (char*)Sh[0] + (size_t)f * 16);
    gld_lds16(Vt + ((size_t)b * DD + n0 + row) * TT + 0 + srcc, (char*)Sh[1] + (size_t)f * 16);
  }
  fv4 acc[2][4] = {};
  for (int g = 0; g < 32; ++g) {
    asm volatile("s_waitcnt vmcnt(0) lgkmcnt(0)\n\ts_barrier" ::: "memory");
    if (g < 31) {
      const int kt = (g + 1) * 64;
      char* At = (char*)Sh[((g & 1) ^ 1) * 2];
      char* Bt = (char*)Sh[((g & 1) ^ 1) * 2 + 1];
      #pragma unroll
      for (int j = 0; j < 2; ++j) {
        int f = j * 512 + t;
        int row = f >> 3, c8 = f & 7;
        int srcc = (c8 ^ (row & 7)) << 3;
        gld_lds16(P + ((size_t)b * TT + m0 + row) * TT + kt + srcc, At + (size_t)f * 16);
        gld_lds16(Vt + ((size_t)b * DD + n0 + row) * TT + kt + srcc, Bt + (size_t)f * 16);
      }
    }
    const char* At = (const char*)Sh[(g & 1) * 2];
    const char* Bt = (const char*)Sh[(g & 1) * 2 + 1];
    #pragma unroll
    for (int ks = 0; ks < 2; ++ks) {
      bv8 af[2], bfr[4];
      #pragma unroll
      for (int i = 0; i < 2; ++i) {
        int ra = wrg + i * 16 + l15;
        af[i] = *(bv8*)(At + ((ra * 128 + ks * 64 + (l4 * 16)) ^ ((ra & 7) << 4)));
      }
      #pragma unroll
      for (int i = 0; i < 4; ++i) {
        int rb = wcg + i * 16 + l15;
        bfr[i] = *(bv8*)(Bt + ((rb * 128 + ks * 64 + (l4 * 16)) ^ ((rb & 7) << 4)));
      }
      #pragma unroll
      for (int mi = 0; mi < 2; ++mi)
        #pragma unroll
        for (int ni = 0; ni < 4; ++ni)
          acc[mi][ni] = __builtin_amdgcn_mfma_f32_16x16x32_bf16(af[mi], bfr[ni], acc[mi][ni], 0, 0, 0);
    }
  }
  #pragma unroll
  for (int mi = 0; mi < 2; ++mi)
    #pragma unroll
    for (int r = 0; r < 4; ++r) {
      int ml = wrg + mi * 16 + (l4 << 2) + r;
      int gm = m0 + ml;
      float inv = 1.0f / Lrow[ml];
      #pragma unroll
      for (int ni = 0; ni < 4; ++ni) {
        int gn = n0 + wcg + ni * 16 + l15;
        __builtin_nontemporal_store(acc[mi][ni][r] * inv,
                                    &Out[((size_t)b * TT + gm) * DD + gn]);
      }
    }
}

extern "C" void kernel_launch(void* const* d_in, const int* in_sizes, int n_in,
                              void* d_out, int out_size, void* d_ws, size_t ws_size,
                              hipStream_t stream) {
  const float* ft_q = (const float*)d_in[0];
  const float* ft_k = (const float*)d_in[1];
  const float* ft_v = (const float*)d_in[2];
  const float* mask = (const float*)d_in[3];
  const float* Wq   = (const float*)d_in[4];
  const float* Wk   = (const float*)d_in[5];
  const float* Wv   = (const float*)d_in[6];
  float* Out = (float*)d_out;

  const size_t nBTD = (size_t)BB * TT * DD;   // 8,388,608
  const size_t nBTT = (size_t)BB * TT * TT;   // 33,554,432
  short* Qb = (short*)d_ws;
  short* Kb = Qb + nBTD;
  short* Vt = Kb + nBTD;
  short* Pq = Vt + nBTD;
  short* Wb = Pq + nBTT;                      // 3 x 512 x 512 bf16
  float* Lpart = (float*)(Wb + (size_t)3 * DD * DD);  // [16][B*T]

  k_castw<<<dim3(DD * DD / 8 / 256, 3), 256, 0, stream>>>(Wq, Wk, Wv, Wb);
  k_proj2<<<dim3(TT * BB / 128, DD / 128, 3), 512, 0, stream>>>(ft_q, ft_k, ft_v, Wb, Qb, Kb, Vt);
  k_sgemm<<<dim3(TT / 128, TT / 128, BB), 512, 0, stream>>>(Qb, Kb, mask, Pq, Lpart);
  k_pv<<<dim3(TT / 128, DD / 128, BB), 512, 0, stream>>>(Pq, Vt, Lpart, Out);
}